// Round 9
// baseline (783.155 us; speedup 1.0000x reference)
//
#include <hip/hip_runtime.h>
#include <hip/hip_bf16.h>
#include <cstddef>

#define LYR 2
#define NH 8
#define HID 512
#define SEQ 1024
#define BATCH 4
#define WBAND 34
#define MROWS (BATCH*SEQ)   // 4096

typedef __attribute__((ext_vector_type(8))) short short8;
typedef __attribute__((ext_vector_type(4))) float f32x4;

__device__ __forceinline__ ushort bf_hi(float x) {
  return (ushort)(__float_as_uint(x) >> 16);
}
__device__ __forceinline__ float bf_res(float x) {
  return x - __uint_as_float(__float_as_uint(x) & 0xffff0000u);
}
__device__ __forceinline__ float rec1(ushort h, ushort l) {
  return __uint_as_float((uint)h << 16) + __uint_as_float((uint)l << 16);
}
__device__ __forceinline__ void cvt4(float4 v, ushort4& h, ushort4& l) {
  h.x = bf_hi(v.x); h.y = bf_hi(v.y); h.z = bf_hi(v.z); h.w = bf_hi(v.w);
  l.x = bf_hi(bf_res(v.x)); l.y = bf_hi(bf_res(v.y));
  l.z = bf_hi(bf_res(v.z)); l.w = bf_hi(bf_res(v.w));
}

#define GLOAD16(gp, lp)                                                        \
  __builtin_amdgcn_global_load_lds(                                            \
      (const __attribute__((address_space(1))) void*)(gp),                     \
      (__attribute__((address_space(3))) void*)(lp), 16, 0, 0)

// ------------- split-precision bf16x3 GEMM -------------
// C[4096,N] = rec(A) @ rec(W)^T + bias. Epilogue modes:
//   Cf != 0            : plain fp32 C
//   else if Yh != 0    : fused highway (W pre-permuted n/g interleave), writes
//                        Chi/Clo planes [4096][512]; optional residual Xh/Xl,
//                        optional fp32 out store (stride 1024)
//   else               : hi/lo planes C
__global__ __launch_bounds__(256, 2)
void gemm_hl(const ushort* __restrict__ Ahi, const ushort* __restrict__ Alo,
             const ushort* __restrict__ Whi, const ushort* __restrict__ Wlo,
             const float* __restrict__ bias, float* __restrict__ Cf,
             ushort* __restrict__ Chi, ushort* __restrict__ Clo,
             const ushort* __restrict__ Yh, const ushort* __restrict__ Yl,
             const ushort* __restrict__ Xh, const ushort* __restrict__ Xl,
             float* __restrict__ outp, int N) {
  __shared__ ushort lds[4 * 4096];  // planes: Ahi Alo Bhi Blo, each [128][32]
  const int tid = threadIdx.x;
  const int lane = tid & 63, wid = tid >> 6;
  const int wm = wid >> 1, wn = wid & 1;
  const int fr = lane & 15, fq = lane >> 4;
  const int bm = blockIdx.y * 128, bn = blockIdx.x * 128;

  f32x4 acc[4][4] = {};

  for (int k0 = 0; k0 < 512; k0 += 32) {
    __syncthreads();
#pragma unroll
    for (int i = 0; i < 2; ++i) {
      const int c = tid + 256 * i;
      const int row = c >> 2, col = (c & 3) * 8;
      const size_t ga = (size_t)(bm + row) * 512 + k0 + col;
      const size_t gb = (size_t)(bn + row) * 512 + k0 + col;
      GLOAD16(Ahi + ga, &lds[0 * 4096 + c * 8]);
      GLOAD16(Alo + ga, &lds[1 * 4096 + c * 8]);
      GLOAD16(Whi + gb, &lds[2 * 4096 + c * 8]);
      GLOAD16(Wlo + gb, &lds[3 * 4096 + c * 8]);
    }
    __syncthreads();

    short8 ah[4], al[4], bh[4], bl[4];
#pragma unroll
    for (int m = 0; m < 4; ++m) {
      const int ro = (wm * 64 + m * 16 + fr) * 32 + fq * 8;
      ah[m] = *(const short8*)&lds[0 * 4096 + ro];
      al[m] = *(const short8*)&lds[1 * 4096 + ro];
    }
#pragma unroll
    for (int n = 0; n < 4; ++n) {
      const int ro = (wn * 64 + n * 16 + fr) * 32 + fq * 8;
      bh[n] = *(const short8*)&lds[2 * 4096 + ro];
      bl[n] = *(const short8*)&lds[3 * 4096 + ro];
    }
#pragma unroll
    for (int m = 0; m < 4; ++m)
#pragma unroll
      for (int n = 0; n < 4; ++n) {
        acc[m][n] = __builtin_amdgcn_mfma_f32_16x16x32_bf16(ah[m], bh[n], acc[m][n], 0, 0, 0);
        acc[m][n] = __builtin_amdgcn_mfma_f32_16x16x32_bf16(ah[m], bl[n], acc[m][n], 0, 0, 0);
        acc[m][n] = __builtin_amdgcn_mfma_f32_16x16x32_bf16(al[m], bh[n], acc[m][n], 0, 0, 0);
      }
  }

  // C/D: col = lane&15, row = (lane>>4)*4 + reg
  const int cn0 = bn + wn * 64 + fr;
  if (Yh) {
    // fused highway epilogue: permuted col -> channel col>>1, type col&1
    const int fo = fr & 1;
#pragma unroll
    for (int n = 0; n < 4; ++n) {
      const int col = cn0 + n * 16;
      const float bv = bias[(col >> 1) + (col & 1) * 512];
      const int ch = col >> 1;
#pragma unroll
      for (int m = 0; m < 4; ++m) {
        const int row0 = bm + wm * 64 + m * 16 + fq * 4;
#pragma unroll
        for (int r = 0; r < 4; ++r) {
          const float v = acc[m][n][r] + bv;
          const float pv = __shfl_xor(v, 1);
          const float nval = fo ? pv : v;
          const float gval = fo ? v : pv;
          const float g = 1.f / (1.f + __expf(-gval));
          const size_t yo = (size_t)(row0 + r) * 512 + ch;
          float ynew = g * rec1(Yh[yo], Yl[yo]) + (1.f - g) * fmaxf(nval, 0.f);
          if (Xh) ynew += rec1(Xh[yo], Xl[yo]);
          if (!fo) {
            Chi[yo] = bf_hi(ynew);
            Clo[yo] = bf_hi(bf_res(ynew));
            if (outp) outp[(size_t)(row0 + r) * 1024 + ch] = ynew;
          }
        }
      }
    }
  } else {
#pragma unroll
    for (int n = 0; n < 4; ++n) {
      const int col = cn0 + n * 16;
      const float bv = bias[col];
#pragma unroll
      for (int m = 0; m < 4; ++m) {
        const int row0 = bm + wm * 64 + m * 16 + fq * 4;
#pragma unroll
        for (int r = 0; r < 4; ++r) {
          const float v = acc[m][n][r] + bv;
          const size_t o = (size_t)(row0 + r) * N + col;
          if (Cf) {
            Cf[o] = v;
          } else {
            Chi[o] = bf_hi(v);
            Clo[o] = bf_hi(bf_res(v));
          }
        }
      }
    }
  }
}

// ------------- banded attention, 16-query tiles -------------
// QKV fp32 [4096][1536] rows = q|k|v. Block = (16 queries, head, batch).
// 49 K/V rows staged in LDS (25.5 KB -> 6 blocks/CU). Wave handles 4 queries.
// NOTE: K reads from LDS are float2 ONLY — KSTR=66 rows are 8B-aligned, a
// float4 (ds_read_b128) there would be misaligned for odd rows.
#define KSTR 66
__global__ __launch_bounds__(256)
void band_attn3(const float* __restrict__ QKV, const float* __restrict__ rel,
                ushort* __restrict__ Oh, ushort* __restrict__ Ol, int left) {
  __shared__ float Kt[49 * KSTR];
  __shared__ float Vt[49 * 64];
  const int tid = threadIdx.x, lane = tid & 63, w = tid >> 6;
  const int i0 = blockIdx.x * 16, h = blockIdx.y, b = blockIdx.z;
  const int j0 = left ? i0 - 33 : i0;
  const size_t base = (size_t)b * SEQ * 1536 + h * 64;

  // stage K,V rows j0..j0+48 (zero-fill OOB)
#pragma unroll
  for (int s = 0; s < 7; ++s) {
    const int r = s * 8 + (tid >> 5);
    const int c = (tid & 31) * 2;
    if (r < 49) {
      const int j = j0 + r;
      float2 kv = make_float2(0.f, 0.f), vv = make_float2(0.f, 0.f);
      if (j >= 0 && j < SEQ) {
        kv = *(const float2*)(QKV + base + (size_t)j * 1536 + 512 + c);
        vv = *(const float2*)(QKV + base + (size_t)j * 1536 + 1024 + c);
      }
      Kt[r * KSTR + c] = kv.x; Kt[r * KSTR + c + 1] = kv.y;
      Vt[r * 64 + c] = vv.x;   Vt[r * 64 + c + 1] = vv.y;
    }
  }
  __syncthreads();

  const int t = lane;
  const float relb = (t < WBAND) ? rel[h * WBAND + t] : 0.f;

#pragma unroll 2
  for (int qq = 0; qq < 4; ++qq) {
    const int qi = w * 4 + qq;
    const int i = i0 + qi;
    const int j = left ? (i - 33 + t) : (i + t);
    const bool val = (t < WBAND) && (j >= 0) && (j < SEQ);
    const int krow = (qi + t > 48) ? 48 : (qi + t);

    // score: 4 independent fma chains, float2 loads (8B-aligned everywhere)
    const float2* q2 = (const float2*)(QKV + base + (size_t)i * 1536);
    const float2* kp = (const float2*)&Kt[krow * KSTR];
    float sa0 = 0.f, sa1 = 0.f, sa2 = 0.f, sa3 = 0.f;
#pragma unroll
    for (int c = 0; c < 32; c += 4) {
      const float2 q0 = q2[c],     k0 = kp[c];
      const float2 q1 = q2[c + 1], k1 = kp[c + 1];
      const float2 qv = q2[c + 2], k2 = kp[c + 2];
      const float2 q3 = q2[c + 3], k3 = kp[c + 3];
      sa0 = fmaf(q0.x, k0.x, fmaf(q0.y, k0.y, sa0));
      sa1 = fmaf(q1.x, k1.x, fmaf(q1.y, k1.y, sa1));
      sa2 = fmaf(qv.x, k2.x, fmaf(qv.y, k2.y, sa2));
      sa3 = fmaf(q3.x, k3.x, fmaf(q3.y, k3.y, sa3));
    }
    const float s = (sa0 + sa1) + (sa2 + sa3);
    float score = val ? (s * 0.125f + relb) : -1e30f;

    float m = score;
#pragma unroll
    for (int off = 32; off; off >>= 1) m = fmaxf(m, __shfl_xor(m, off));
    float p = __expf(score - m);
    float sum = p;
#pragma unroll
    for (int off = 32; off; off >>= 1) sum += __shfl_xor(sum, off);
    p /= sum;

    // PV: lane = d, 2 accumulator chains
    float o0 = 0.f, o1 = 0.f;
    const float* vcol = &Vt[qi * 64 + lane];
#pragma unroll
    for (int tt = 0; tt < WBAND; tt += 2) {
      o0 = fmaf(__shfl(p, tt), vcol[tt * 64], o0);
      o1 = fmaf(__shfl(p, tt + 1), vcol[(tt + 1) * 64], o1);
    }
    const float o = o0 + o1;

    const size_t oidx = ((size_t)b * SEQ + i) * 512 + h * 64 + lane;
    Oh[oidx] = bf_hi(o);
    Ol[oidx] = bf_hi(bf_res(o));
  }
}

// ------------- fp32 -> hi/lo split (activations) -------------
__global__ __launch_bounds__(256)
void convert_pair(const float* __restrict__ src, ushort* __restrict__ h,
                  ushort* __restrict__ l, int n4) {
  const int idx = blockIdx.x * 256 + threadIdx.x;
  if (idx >= n4) return;
  const float4 v = ((const float4*)src)[idx];
  ushort4 hh, ll;
  cvt4(v, hh, ll);
  ((ushort4*)h)[idx] = hh;
  ((ushort4*)l)[idx] = ll;
}

// per-pass weights -> hi/lo planes. qkv rows plain; highway rows permuted so
// permuted row r = original row (r>>1) + (r&1)*512 (nonlin/gate interleave).
__global__ __launch_bounds__(256)
void convert_w(const float* __restrict__ qsrc, const float* __restrict__ hsrc,
               ushort* __restrict__ h, ushort* __restrict__ l) {
  const int idx = blockIdx.x * 256 + threadIdx.x;  // 0..524287 float4 groups
  float4 v;
  if (idx < 262144) {
    v = ((const float4*)qsrc)[idx];
  } else {
    const int rel = idx - 262144;
    const int k2 = rel >> 17;
    const int rr = rel & 131071;
    const int r = rr >> 7, c4 = rr & 127;
    const int srow = (r >> 1) + (r & 1) * 512;
    v = ((const float4*)hsrc)[(k2 * 1024 + srow) * 128 + c4];
  }
  ushort4 hh, ll;
  cvt4(v, hh, ll);
  ((ushort4*)h)[idx] = hh;
  ((ushort4*)l)[idx] = ll;
}

extern "C" void kernel_launch(void* const* d_in, const int* in_sizes, int n_in,
                              void* d_out, int out_size, void* d_ws, size_t ws_size,
                              hipStream_t stream) {
  const float* x_in  = (const float*)d_in[0];
  const float* qkv_w = (const float*)d_in[2];
  const float* qkv_b = (const float*)d_in[3];
  const float* rel   = (const float*)d_in[4];
  const float* hw_w  = (const float*)d_in[5];
  const float* hw_b  = (const float*)d_in[6];
  float* out = (float*)d_out;
  char* ws = (char*)d_ws;

  const size_t ACT = (size_t)MROWS * HID * 2;  // 4 MB per bf16 plane
  float* QKVbuf = (float*)ws;                  // 25.2 MB fp32
  // TMP planes alias QKVbuf (dead after attention)
  ushort* T1H = (ushort*)ws;
  ushort* T1L = (ushort*)(ws + ACT);
  ushort* T2H = (ushort*)(ws + 2 * ACT);
  ushort* T2L = (ushort*)(ws + 3 * ACT);
  char* q = ws + (size_t)MROWS * 1536 * 4;
  ushort* ATTH = (ushort*)q;            q += ACT;
  ushort* ATTL = (ushort*)q;            q += ACT;
  ushort* actH[4], *actL[4];
  for (int i = 0; i < 4; ++i) { actH[i] = (ushort*)q; q += ACT; actL[i] = (ushort*)q; q += ACT; }
  ushort* WPH = (ushort*)q;             q += (size_t)2097152 * 2;
  ushort* WPL = (ushort*)q;

  convert_pair<<<2048, 256, 0, stream>>>(x_in, actH[0], actL[0], MROWS * HID / 4);

  int cur[2] = {0, 0};
  const int alt_idx[2][2] = {{1, 2}, {0, 3}};

  for (int l = 0; l < LYR; ++l) {
    for (int dir = 0; dir < 2; ++dir) {
      const int ci = cur[dir];
      const int ai = alt_idx[l][dir];
      const float* bq = qkv_b + (size_t)(l * 2 + dir) * 4 * HID;
      const float* bh = hw_b + (size_t)(l * 2 + dir) * 2 * 1024;

      convert_w<<<2048, 256, 0, stream>>>(
          qkv_w + (size_t)(l * 2 + dir) * 4 * HID * HID,
          hw_w + (size_t)(l * 2 + dir) * 2 * 1024 * HID, WPH, WPL);

      // QKV projection -> fp32 [4096][1536]
      gemm_hl<<<dim3(12, 32), 256, 0, stream>>>(
          actH[ci], actL[ci], WPH, WPL, bq, QKVbuf,
          nullptr, nullptr, nullptr, nullptr, nullptr, nullptr, nullptr, 1536);

      band_attn3<<<dim3(64, NH, BATCH), 256, 0, stream>>>(
          QKVbuf, rel + (size_t)(l * 2 + dir) * NH * WBAND, ATTH, ATTL, dir == 0);

      // out-projection -> T1 planes
      gemm_hl<<<dim3(4, 32), 256, 0, stream>>>(
          ATTH, ATTL, WPH + 786432, WPL + 786432, bq + 3 * HID, nullptr,
          T1H, T1L, nullptr, nullptr, nullptr, nullptr, nullptr, 512);

      // highway 1 (fused epilogue): A=T1, Y_old=T1 -> T2 planes
      gemm_hl<<<dim3(8, 32), 256, 0, stream>>>(
          T1H, T1L, WPH + 1048576, WPL + 1048576, bh, nullptr,
          T2H, T2L, T1H, T1L, nullptr, nullptr, nullptr, 1024);

      // highway 2 (fused): A=T2, Y_old=T2, +residual(act[ci]) if l>0, +out store
      gemm_hl<<<dim3(8, 32), 256, 0, stream>>>(
          T2H, T2L, WPH + 1572864, WPL + 1572864, bh + 1024, nullptr,
          actH[ai], actL[ai], T2H, T2L,
          (l > 0) ? actH[ci] : nullptr, (l > 0) ? actL[ci] : nullptr,
          out + (size_t)l * MROWS * 1024 + dir * 512, 1024);

      cur[dir] = ai;
    }
  }
}

// Round 14
// 601.651 us; speedup vs baseline: 1.3017x; 1.3017x over previous
//
#include <hip/hip_runtime.h>
#include <hip/hip_bf16.h>
#include <cstddef>

#define LYR 2
#define NH 8
#define HID 512
#define SEQ 1024
#define BATCH 4
#define WBAND 34

typedef __attribute__((ext_vector_type(8))) short short8;
typedef __attribute__((ext_vector_type(4))) float f32x4;

__device__ __forceinline__ ushort bf_hi(float x) {
  return (ushort)(__float_as_uint(x) >> 16);
}
__device__ __forceinline__ float bf_res(float x) {
  return x - __uint_as_float(__float_as_uint(x) & 0xffff0000u);
}
__device__ __forceinline__ ushort bf_rn(float x) {  // round-to-nearest-even
  const uint u = __float_as_uint(x);
  return (ushort)((u + 0x7fffu + ((u >> 16) & 1u)) >> 16);
}
__device__ __forceinline__ float bf2f(ushort h) {
  return __uint_as_float((uint)h << 16);
}
__device__ __forceinline__ float rec2(ushort h, ushort l) { return bf2f(h) + bf2f(l); }
__device__ __forceinline__ void cvt4(float4 v, ushort4& h, ushort4& l) {
  h.x = bf_hi(v.x); h.y = bf_hi(v.y); h.z = bf_hi(v.z); h.w = bf_hi(v.w);
  l.x = bf_hi(bf_res(v.x)); l.y = bf_hi(bf_res(v.y));
  l.z = bf_hi(bf_res(v.z)); l.w = bf_hi(bf_res(v.w));
}

#define GLOAD16(gp, lp)                                                        \
  __builtin_amdgcn_global_load_lds(                                            \
      (const __attribute__((address_space(1))) void*)(gp),                     \
      (__attribute__((address_space(3))) void*)(lp), 16, 0, 0)

// ---------------- split-precision GEMM, dir-merged via blockIdx.z ----------
// C[4096,N] = rec(A) @ rec(W)^T + bias.  A: hi/lo planes if ALO else bf16.
// Epilogue: Yh!=0 -> fused highway (Y pair, optional X pair, optional fp32
// out store; C pair if Clo else single RTN); else C pair/single, stride N.
template <int ALO>
__global__ __launch_bounds__(256, 2)
void gemm_t(const ushort* __restrict__ Ahi, const ushort* __restrict__ Alo, int As,
            const ushort* __restrict__ Whi, const ushort* __restrict__ Wlo, int Ws,
            const float* __restrict__ bias, int bs,
            ushort* __restrict__ Chi, ushort* __restrict__ Clo, int Cs,
            const ushort* __restrict__ Yh, const ushort* __restrict__ Yl, int Ys,
            const ushort* __restrict__ Xh, const ushort* __restrict__ Xl, int Xs,
            float* __restrict__ outp, int outs, int N) {
  __shared__ ushort lds[4 * 4096];  // planes: Ahi Alo Bhi Blo, each [128][32]
  const int z = blockIdx.z;
  Ahi += (size_t)z * As;
  if (ALO) Alo += (size_t)z * As;
  Whi += (size_t)z * Ws; Wlo += (size_t)z * Ws;
  bias += (size_t)z * bs;
  Chi += (size_t)z * Cs;
  if (Clo) Clo += (size_t)z * Cs;
  if (Yh) { Yh += (size_t)z * Ys; Yl += (size_t)z * Ys; }
  if (Xh) { Xh += (size_t)z * Xs; Xl += (size_t)z * Xs; }
  if (outp) outp += (size_t)z * outs;

  const int tid = threadIdx.x;
  const int lane = tid & 63, wid = tid >> 6;
  const int wm = wid >> 1, wn = wid & 1;
  const int fr = lane & 15, fq = lane >> 4;
  const int bm = blockIdx.y * 128, bn = blockIdx.x * 128;

  f32x4 acc[4][4] = {};

  for (int k0 = 0; k0 < 512; k0 += 32) {
    __syncthreads();
#pragma unroll
    for (int i = 0; i < 2; ++i) {
      const int c = tid + 256 * i;
      const int row = c >> 2, col = (c & 3) * 8;
      const size_t ga = (size_t)(bm + row) * 512 + k0 + col;
      const size_t gb = (size_t)(bn + row) * 512 + k0 + col;
      GLOAD16(Ahi + ga, &lds[0 * 4096 + c * 8]);
      if (ALO) GLOAD16(Alo + ga, &lds[1 * 4096 + c * 8]);
      GLOAD16(Whi + gb, &lds[2 * 4096 + c * 8]);
      GLOAD16(Wlo + gb, &lds[3 * 4096 + c * 8]);
    }
    __syncthreads();

    short8 ah[4], al[4], bh[4], bl[4];
#pragma unroll
    for (int m = 0; m < 4; ++m) {
      const int ro = (wm * 64 + m * 16 + fr) * 32 + fq * 8;
      ah[m] = *(const short8*)&lds[0 * 4096 + ro];
      if (ALO) al[m] = *(const short8*)&lds[1 * 4096 + ro];
    }
#pragma unroll
    for (int n = 0; n < 4; ++n) {
      const int ro = (wn * 64 + n * 16 + fr) * 32 + fq * 8;
      bh[n] = *(const short8*)&lds[2 * 4096 + ro];
      bl[n] = *(const short8*)&lds[3 * 4096 + ro];
    }
#pragma unroll
    for (int m = 0; m < 4; ++m)
#pragma unroll
      for (int n = 0; n < 4; ++n) {
        acc[m][n] = __builtin_amdgcn_mfma_f32_16x16x32_bf16(ah[m], bh[n], acc[m][n], 0, 0, 0);
        acc[m][n] = __builtin_amdgcn_mfma_f32_16x16x32_bf16(ah[m], bl[n], acc[m][n], 0, 0, 0);
        if (ALO)
          acc[m][n] = __builtin_amdgcn_mfma_f32_16x16x32_bf16(al[m], bh[n], acc[m][n], 0, 0, 0);
      }
  }

  // C/D: col = lane&15, row = (lane>>4)*4 + reg
  const int cn0 = bn + wn * 64 + fr;
  if (Yh) {
    const int fo = fr & 1;
#pragma unroll
    for (int n = 0; n < 4; ++n) {
      const int col = cn0 + n * 16;
      const float bv = bias[(col >> 1) + (col & 1) * 512];
      const int ch = col >> 1;
#pragma unroll
      for (int m = 0; m < 4; ++m) {
        const int row0 = bm + wm * 64 + m * 16 + fq * 4;
#pragma unroll
        for (int r = 0; r < 4; ++r) {
          const float v = acc[m][n][r] + bv;
          const float pv = __shfl_xor(v, 1);
          const float nval = fo ? pv : v;
          const float gval = fo ? v : pv;
          const float g = 1.f / (1.f + __expf(-gval));
          const size_t yo = (size_t)(row0 + r) * 512 + ch;
          float ynew = g * rec2(Yh[yo], Yl[yo]) + (1.f - g) * fmaxf(nval, 0.f);
          if (Xh) ynew += rec2(Xh[yo], Xl[yo]);
          if (!fo) {
            if (Clo) { Chi[yo] = bf_hi(ynew); Clo[yo] = bf_hi(bf_res(ynew)); }
            else       Chi[yo] = bf_rn(ynew);
            if (outp) outp[(size_t)(row0 + r) * 1024 + ch] = ynew;
          }
        }
      }
    }
  } else {
#pragma unroll
    for (int n = 0; n < 4; ++n) {
      const int col = cn0 + n * 16;
      const float bv = bias[col];
#pragma unroll
      for (int m = 0; m < 4; ++m) {
        const int row0 = bm + wm * 64 + m * 16 + fq * 4;
#pragma unroll
        for (int r = 0; r < 4; ++r) {
          const float v = acc[m][n][r] + bv;
          const size_t o = (size_t)(row0 + r) * N + col;
          if (Clo) { Chi[o] = bf_hi(v); Clo[o] = bf_hi(bf_res(v)); }
          else       Chi[o] = bf_rn(v);
        }
      }
    }
  }
}

// ------------- banded attention, 16-query tiles, dir-merged, bf16 QKV ------
// grid (64, NH, 8): z = b + dir*4. QKV bf16 [dir][4096][1536], dir stride
// 6291456 u16. Output ATT bf16 [dir][4096][512]. K reads float2-only.
#define KSTR 66
__global__ __launch_bounds__(256)
void band_attn4(const ushort* __restrict__ QKV, const float* __restrict__ rel,
                ushort* __restrict__ O) {
  __shared__ float Kt[49 * KSTR];
  __shared__ float Vt[49 * 64];
  const int zz = blockIdx.z;
  const int b = zz & 3, dir = zz >> 2;
  const int left = (dir == 0);
  QKV += (size_t)dir * 6291456;
  rel += dir * (NH * WBAND);
  O += (size_t)dir * 2097152;

  const int tid = threadIdx.x, lane = tid & 63, w = tid >> 6;
  const int i0 = blockIdx.x * 16, h = blockIdx.y;
  const int j0 = left ? i0 - 33 : i0;
  const size_t base = (size_t)b * SEQ * 1536 + h * 64;

#pragma unroll
  for (int s = 0; s < 7; ++s) {
    const int r = s * 8 + (tid >> 5);
    const int c = (tid & 31) * 2;
    if (r < 49) {
      const int j = j0 + r;
      float2 kv = make_float2(0.f, 0.f), vv = make_float2(0.f, 0.f);
      if (j >= 0 && j < SEQ) {
        const ushort2 k2 = *(const ushort2*)(QKV + base + (size_t)j * 1536 + 512 + c);
        const ushort2 v2 = *(const ushort2*)(QKV + base + (size_t)j * 1536 + 1024 + c);
        kv = make_float2(bf2f(k2.x), bf2f(k2.y));
        vv = make_float2(bf2f(v2.x), bf2f(v2.y));
      }
      Kt[r * KSTR + c] = kv.x; Kt[r * KSTR + c + 1] = kv.y;
      Vt[r * 64 + c] = vv.x;   Vt[r * 64 + c + 1] = vv.y;
    }
  }
  __syncthreads();

  const int t = lane;
  const float relb = (t < WBAND) ? rel[h * WBAND + t] : 0.f;

#pragma unroll 2
  for (int qq = 0; qq < 4; ++qq) {
    const int qi = w * 4 + qq;
    const int i = i0 + qi;
    const int j = left ? (i - 33 + t) : (i + t);
    const bool val = (t < WBAND) && (j >= 0) && (j < SEQ);
    const int krow = (qi + t > 48) ? 48 : (qi + t);

    const ushort2* q2 = (const ushort2*)(QKV + base + (size_t)i * 1536);
    const float2* kp = (const float2*)&Kt[krow * KSTR];
    float sa0 = 0.f, sa1 = 0.f, sa2 = 0.f, sa3 = 0.f;
#pragma unroll
    for (int c = 0; c < 32; c += 4) {
      const ushort2 qa = q2[c],     qb = q2[c + 1];
      const ushort2 qc = q2[c + 2], qd = q2[c + 3];
      const float2 k0 = kp[c],     k1 = kp[c + 1];
      const float2 k2 = kp[c + 2], k3 = kp[c + 3];
      sa0 = fmaf(bf2f(qa.x), k0.x, fmaf(bf2f(qa.y), k0.y, sa0));
      sa1 = fmaf(bf2f(qb.x), k1.x, fmaf(bf2f(qb.y), k1.y, sa1));
      sa2 = fmaf(bf2f(qc.x), k2.x, fmaf(bf2f(qc.y), k2.y, sa2));
      sa3 = fmaf(bf2f(qd.x), k3.x, fmaf(bf2f(qd.y), k3.y, sa3));
    }
    const float s = (sa0 + sa1) + (sa2 + sa3);
    float score = val ? (s * 0.125f + relb) : -1e30f;

    float m = score;
#pragma unroll
    for (int off = 32; off; off >>= 1) m = fmaxf(m, __shfl_xor(m, off));
    float p = __expf(score - m);
    float sum = p;
#pragma unroll
    for (int off = 32; off; off >>= 1) sum += __shfl_xor(sum, off);
    p /= sum;

    float o0 = 0.f, o1 = 0.f;
    const float* vcol = &Vt[qi * 64 + lane];
#pragma unroll
    for (int tt = 0; tt < WBAND; tt += 2) {
      o0 = fmaf(__shfl(p, tt), vcol[tt * 64], o0);
      o1 = fmaf(__shfl(p, tt + 1), vcol[(tt + 1) * 64], o1);
    }
    O[((size_t)b * SEQ + i) * 512 + h * 64 + lane] = bf_rn(o0 + o1);
  }
}

// ------------- fp32 -> hi/lo split (initial x) -------------
__global__ __launch_bounds__(256)
void convert_pair(const float* __restrict__ src, ushort* __restrict__ h,
                  ushort* __restrict__ l, int n4) {
  const int idx = blockIdx.x * 256 + threadIdx.x;
  if (idx >= n4) return;
  const float4 v = ((const float4*)src)[idx];
  ushort4 hh, ll;
  cvt4(v, hh, ll);
  ((ushort4*)h)[idx] = hh;
  ((ushort4*)l)[idx] = ll;
}

// ------------- per-layer weights (both dirs) -> hi/lo planes -------------
// 1,048,576 float4 groups: dir = idx>>19; per dir [qkv 262144][hw 262144];
// highway rows permuted: permuted row r <- original (r>>1) + (r&1)*512.
__global__ __launch_bounds__(256)
void convert_w(const float* __restrict__ qsrc, const float* __restrict__ hsrc,
               ushort* __restrict__ h, ushort* __restrict__ l) {
  const int idx = blockIdx.x * 256 + threadIdx.x;
  const int dir = idx >> 19;
  const int i19 = idx & 524287;
  float4 v;
  if (i19 < 262144) {
    v = ((const float4*)qsrc)[dir * 262144 + i19];
  } else {
    const int relg = i19 - 262144;
    const int k2 = relg >> 17;
    const int rr = relg & 131071;
    const int r = rr >> 7, c4 = rr & 127;
    const int srow = (r >> 1) + (r & 1) * 512;
    v = ((const float4*)hsrc)[dir * 262144 + (k2 * 1024 + srow) * 128 + c4];
  }
  ushort4 hh, ll;
  cvt4(v, hh, ll);
  ((ushort4*)h)[idx] = hh;
  ((ushort4*)l)[idx] = ll;
}

extern "C" void kernel_launch(void* const* d_in, const int* in_sizes, int n_in,
                              void* d_out, int out_size, void* d_ws, size_t ws_size,
                              hipStream_t stream) {
  const float* x_in  = (const float*)d_in[0];
  const float* qkv_w = (const float*)d_in[2];
  const float* qkv_b = (const float*)d_in[3];
  const float* rel   = (const float*)d_in[4];
  const float* hw_w  = (const float*)d_in[5];
  const float* hw_b  = (const float*)d_in[6];
  float* out = (float*)d_out;
  ushort* W16 = (ushort*)d_ws;

  // ---- workspace: EXACTLY 75,497,472 B (72 MiB) — proven-safe envelope.
  // u16 offsets:
  //   [0,        12582912): QK bf16 [2][4096][1536] (dir stride 6291456)
  //      after attn, dead -> T1H [2] @0, T1L [2] @4194304, T2H [2] @8388608
  //      (each dir stride 2097152); l=1 hw2 dump reuses T1H
  //   [12582912, 16777216): ATT bf16 [2] (dir stride 2097152)
  //   [16777216, 20971520): xH @16777216, xL @18874368 (l=0 only; dead
  //      after l=0 QKV proj) -> T2L [2] (dir stride 2097152)
  //   [20971520, 29360128): G hi/lo [2] (dir stride 4194304; GH, GL=+2097152)
  //   [29360128, 33554432): WPH [2] (dir stride 2097152)
  //   [33554432, 37748736): WPL [2]
  ushort* QK  = W16;
  ushort* T1H = W16;
  ushort* T1L = W16 + 4194304;
  ushort* T2H = W16 + 8388608;
  ushort* ATT = W16 + 12582912;
  ushort* xH  = W16 + 16777216;
  ushort* xL  = W16 + 18874368;
  ushort* T2L = W16 + 16777216;
  ushort* G   = W16 + 20971520;
  ushort* WPH = W16 + 29360128;
  ushort* WPL = W16 + 33554432;

  convert_pair<<<2048, 256, 0, stream>>>(x_in, xH, xL, 524288);

  for (int l = 0; l < LYR; ++l) {
    convert_w<<<4096, 256, 0, stream>>>(
        qkv_w + (size_t)l * 2097152, hw_w + (size_t)l * 2097152, WPH, WPL);

    // QKV projection (A hi/lo) -> QK bf16 [dir][4096][1536]
    gemm_t<1><<<dim3(12, 32, 2), 256, 0, stream>>>(
        l ? G : xH, l ? G + 2097152 : xL, l ? 4194304 : 0,
        WPH, WPL, 2097152,
        qkv_b + (size_t)l * 4096, 2048,
        QK, nullptr, 6291456,
        nullptr, nullptr, 0, nullptr, nullptr, 0, nullptr, 0, 1536);

    band_attn4<<<dim3(64, NH, 8), 256, 0, stream>>>(
        QK, rel + (size_t)l * 2 * NH * WBAND, ATT);

    // out-projection: A = ATT bf16 -> T1 hi/lo (QK region is dead)
    gemm_t<0><<<dim3(4, 32, 2), 256, 0, stream>>>(
        ATT, nullptr, 2097152, WPH + 786432, WPL + 786432, 2097152,
        qkv_b + (size_t)l * 4096 + 1536, 2048,
        T1H, T1L, 2097152,
        nullptr, nullptr, 0, nullptr, nullptr, 0, nullptr, 0, 512);

    // highway 1 (fused): A = T1 pair, Y = T1 pair -> T2 pair
    gemm_t<1><<<dim3(8, 32, 2), 256, 0, stream>>>(
        T1H, T1L, 2097152, WPH + 1048576, WPL + 1048576, 2097152,
        hw_b + (size_t)l * 4096, 2048,
        T2H, T2L, 2097152,
        T1H, T1L, 2097152,
        nullptr, nullptr, 0, nullptr, 0, 1024);

    // highway 2 (fused): A = T2 pair, Y = T2 pair, + residual at l=1, + out
    if (l == 0) {
      gemm_t<1><<<dim3(8, 32, 2), 256, 0, stream>>>(
          T2H, T2L, 2097152, WPH + 1572864, WPL + 1572864, 2097152,
          hw_b + (size_t)l * 4096 + 1024, 2048,
          G, G + 2097152, 4194304,
          T2H, T2L, 2097152,
          nullptr, nullptr, 0,
          out, 512, 1024);
    } else {
      gemm_t<1><<<dim3(8, 32, 2), 256, 0, stream>>>(
          T2H, T2L, 2097152, WPH + 1572864, WPL + 1572864, 2097152,
          hw_b + (size_t)l * 4096 + 1024, 2048,
          T1H, nullptr, 2097152,
          T2H, T2L, 2097152,
          G, G + 2097152, 4194304,
          out + 4194304, 512, 1024);
    }
  }
}